// Round 4
// baseline (95.803 us; speedup 1.0000x reference)
//
#include <hip/hip_runtime.h>

#define TPB 256

typedef float v2f __attribute__((ext_vector_type(2)));

// |v| as max(v,-v): VOP3P has neg modifiers but no abs, so this is 1 pk op.
static __device__ __forceinline__ v2f vabs2(v2f v) {
    return __builtin_elementwise_max(v, -v);
}

// Fused StandardPershomReadout: 3 rational-hat reductions, ONE dispatch,
// every output element written by exactly one block (no atomics, no memset).
//
// f(d) = 1/(1+d) - 1/(1+|R-d|) == (|R-d| - d) / ((1+d)*(1+|R-d|))
// Pairwise reciprocal (quotient trick): 1/a,1/b = (b*rp, a*rp), rp=rcp(a*b)
// -> one quarter-rate v_rcp_f32 per 2 points instead of two.
//
// Decomposition (uniform 65536 point-center pairs per block, 768 blocks =
// 3/CU):
//   part 0  : 512 blocks = 128 rows x 4 center-groups (16 centers) x 4096 pts
//   part 1/2: 128 blocks each = one row x 64 centers x 1024 pts
//
// Part-0 LDS layout: 16 point-segments of 128 pairs, seg strip padded +1
// float4 (pxy) / +1 v2f (pm). A wave reads 4 distinct seg addresses
// (16-lane broadcast groups); the +1 pad shifts each seg by 4 (resp. 2)
// banks -> disjoint bank quads -> conflict-free ds_read_b128/b64.
__global__ __launch_bounds__(TPB) void pershom_kernel(
    const float* __restrict__ h0,  const float* __restrict__ m0,
    const float* __restrict__ h0e, const float* __restrict__ m0e,
    const float* __restrict__ h1e, const float* __restrict__ m1e,
    const float* __restrict__ c0,  const float* __restrict__ r0,
    const float* __restrict__ c0e, const float* __restrict__ r0e,
    const float* __restrict__ c1e, const float* __restrict__ r1e,
    float* __restrict__ out)
{
    __shared__ float4 pxy[16 * 129];   // paired (x0,x1,y0,y1) — 33 KB
    __shared__ v2f    pm [16 * 129];   // paired masks        — 16.5 KB
    __shared__ float  partial[256];

    const int bid = blockIdx.x;
    const int tid = threadIdx.x;
    const v2f one2 = {1.f, 1.f};

    if (bid < 512) {
        // ---------------- part 0: D=2, 16 centers x 4096 points ----------
        const int b     = bid >> 2;
        const int kbase = (bid & 3) * 16;
        const float4* src = (const float4*)(h0 + (size_t)b * 4096 * 2);
        const v2f*    msk = (const v2f*)(m0 + b * 4096);

        // Stage 2048 pairs, seg-padded (+1 per 128-pair strip).
        for (int p = tid; p < 2048; p += TPB) {
            float4 q = src[p];                       // (x0,y0,x1,y1)
            int off  = (p >> 7) * 129 + (p & 127);
            pxy[off] = make_float4(q.x, q.z, q.y, q.w);  // (x0,x1,y0,y1)
            pm [off] = msk[p];
        }

        const int k   = tid & 15;        // center within group
        const int seg = tid >> 4;        // 16 point-segments of 256 pts
        const float cx = c0[2 * (kbase + k)];
        const float cy = c0[2 * (kbase + k) + 1];
        const float R  = fabsf(r0[0]);
        const v2f cx2 = {cx, cx}, cy2 = {cy, cy}, R2v = {R, R};

        __syncthreads();

        v2f acc = {0.f, 0.f};
        const int base = seg * 129;
        #pragma unroll 4
        for (int j = 0; j < 128; ++j) {
            float4 q = pxy[base + j];
            v2f mm   = pm [base + j];
            v2f x01 = {q.x, q.y};
            v2f y01 = {q.z, q.w};
            v2f d   = vabs2(x01 - cx2) + vabs2(y01 - cy2);
            v2f at  = vabs2(R2v - d);
            v2f num = at - d;
            v2f den = (one2 + d) * (one2 + at);
            float rp = __builtin_amdgcn_rcpf(den.x * den.y);
            v2f rc  = {den.y * rp, den.x * rp};
            acc += (mm * num) * rc;
        }

        partial[tid] = acc.x + acc.y;    // [seg*16 + k]
        __syncthreads();
        if (tid < 16) {
            float s = 0.f;
            #pragma unroll
            for (int w = 0; w < 16; ++w) s += partial[w * 16 + tid];
            out[b * 192 + kbase + tid] = s;       // sole writer
        }
    } else {
        // ------------- parts 1/2: D=1, 64 centers x 1024 points ----------
        const float* h; const float* m; const float* cen; const float* rad;
        int outoff;
        if (bid < 640) {
            int b = bid - 512;
            h = h0e + b * 1024; m = m0e + b * 1024;
            cen = c0e; rad = r0e; outoff = b * 192 + 64;
        } else {
            int b = bid - 640;
            h = h1e + b * 1024; m = m1e + b * 1024;
            cen = c1e; rad = r1e; outoff = b * 192 + 128;
        }
        const v2f* src = (const v2f*)h;
        const v2f* msk = (const v2f*)m;
        for (int j = tid; j < 512; j += TPB) {
            v2f x = src[j];
            pxy[j] = make_float4(x.x, x.y, 0.f, 0.f);
            pm [j] = msk[j];
        }

        const int k   = tid & 63;
        const int sub = tid >> 6;
        const float cx = cen[k];
        const float R  = fabsf(rad[0]);
        const v2f cx2 = {cx, cx}, R2v = {R, R};

        __syncthreads();

        v2f acc = {0.f, 0.f};
        const int base = sub * 128;      // wave-uniform -> pure broadcast
        #pragma unroll 4
        for (int j = 0; j < 128; ++j) {
            float4 q = pxy[base + j];
            v2f mm   = pm [base + j];
            v2f x01 = {q.x, q.y};
            v2f d   = vabs2(x01 - cx2);
            v2f at  = vabs2(R2v - d);
            v2f num = at - d;
            v2f den = (one2 + d) * (one2 + at);
            float rp = __builtin_amdgcn_rcpf(den.x * den.y);
            v2f rc  = {den.y * rp, den.x * rp};
            acc += (mm * num) * rc;
        }

        partial[sub * 64 + k] = acc.x + acc.y;
        __syncthreads();
        if (tid < 64) {
            float s = partial[tid] + partial[64 + tid]
                    + partial[128 + tid] + partial[192 + tid];
            out[outoff + tid] = s;                // sole writer
        }
    }
}

extern "C" void kernel_launch(void* const* d_in, const int* in_sizes, int n_in,
                              void* d_out, int out_size, void* d_ws, size_t ws_size,
                              hipStream_t stream) {
    const float* h0  = (const float*)d_in[0];
    const float* m0  = (const float*)d_in[1];
    const float* h0e = (const float*)d_in[2];
    const float* m0e = (const float*)d_in[3];
    const float* h1e = (const float*)d_in[4];
    const float* m1e = (const float*)d_in[5];
    const float* c0  = (const float*)d_in[6];
    const float* r0  = (const float*)d_in[7];
    const float* c0e = (const float*)d_in[8];
    const float* r0e = (const float*)d_in[9];
    const float* c1e = (const float*)d_in[10];
    const float* r1e = (const float*)d_in[11];
    float* out = (float*)d_out;

    dim3 grid(512 + 128 + 128);   // uniform-work blocks, 3 per CU, no memset
    dim3 block(TPB);
    pershom_kernel<<<grid, block, 0, stream>>>(
        h0, m0, h0e, m0e, h1e, m1e, c0, r0, c0e, r0e, c1e, r1e, out);
}